// Round 1
// baseline (562.022 us; speedup 1.0000x reference)
//
#include <hip/hip_runtime.h>
#include <stdint.h>

// ---------------------------------------------------------------------------
// CommonFeatureExtractor on MI355X.  Round 5.
// Changes vs round 4 (541 us; GEMM1 = 121 us @ MfmaUtil 12%, latency-bound):
//  - GEMM1 (AF32): f32 A staged DIRECTLY via global_load_lds into a 16KB f32
//    LDS tile (4x gload16/wave/iter); f32->bf16 conversion moved to the
//    fragment-read side (cvt_pk off the pre-barrier path).  Removes the
//    register round-trip + pack8 + ds_write serialization (m151: reg-staging
//    646 vs gload_lds 874 TF).
//  - LDS swizzles (pre-swizzled per-lane GLOBAL source + swizzled read; LDS
//    dest stays linear, as global_load_lds requires):
//      f32 As:  granule(32B) ^= row&3, half(16B) ^= (row>>2)&1 -> 2-way (free)
//      bf16 As/Bs (all GEMMs): 16B-granule ^= (row>>1)&3       -> 2-way (free)
//    (was 8-way on every fragment read: SQ_LDS_BANK_CONFLICT 4.7M/dispatch)
// Kept: XCD swizzle, merged transpose, buffer aliasing, MODE epilogues.
// ---------------------------------------------------------------------------

typedef __attribute__((ext_vector_type(8))) __bf16 bf16x8;
typedef __attribute__((ext_vector_type(8))) short short8;
typedef __attribute__((ext_vector_type(4))) float floatx4;

__device__ __forceinline__ uint16_t f2bf(float f) {
  __bf16 h = (__bf16)f;                      // native RNE cvt on gfx950
  return __builtin_bit_cast(uint16_t, h);
}
__device__ __forceinline__ float bf2f(uint16_t h) {
  union { uint32_t u; float f; } v; v.u = ((uint32_t)h) << 16;
  return v.f;
}
__device__ __forceinline__ short8 pack8(float4 a, float4 b) {
  union { __bf16 h[8]; short8 s; } u;
  u.h[0] = (__bf16)a.x; u.h[1] = (__bf16)a.y; u.h[2] = (__bf16)a.z; u.h[3] = (__bf16)a.w;
  u.h[4] = (__bf16)b.x; u.h[5] = (__bf16)b.y; u.h[6] = (__bf16)b.z; u.h[7] = (__bf16)b.w;
  return u.s;
}
__device__ __forceinline__ void gload16(const void* g, void* l) {
  __builtin_amdgcn_global_load_lds(
      (const __attribute__((address_space(1))) void*)g,
      (__attribute__((address_space(3))) void*)l, 16, 0, 0);
}

// ------------- merged transpose + convert: dst[n][k] = src[k][n] ------------
// Segments: W1T 3x(32x12)=1152 | W2T 3x(10x32)=960 | ENHT 32x32=1024 |
//           FUST 64x32=2048   -> 5184 blocks total.
__global__ void cfe_transpose_all(const float* __restrict__ bw1, const float* __restrict__ fw1,
                                  const float* __restrict__ pw1, const float* __restrict__ bw2,
                                  const float* __restrict__ fw2, const float* __restrict__ pw2,
                                  const float* __restrict__ enhW, const float* __restrict__ fusW,
                                  uint16_t* __restrict__ W1T, uint16_t* __restrict__ W2T,
                                  uint16_t* __restrict__ ENHT, uint16_t* __restrict__ FUST) {
  int bid = blockIdx.x;
  const float* src; uint16_t* dst; int K, N, Kpad, Npad, bx, by;
  if (bid < 1152) {
    int z = bid / 384, t = bid % 384; bx = t % 32; by = t / 32;
    src = (z == 0) ? bw1 : ((z == 1) ? fw1 : pw1); dst = W1T + (long)z * 384 * 1024;
    K = 1024; N = 300; Kpad = 1024; Npad = 384;
  } else if (bid < 2112) {
    bid -= 1152; int z = bid / 320, t = bid % 320; bx = t % 10; by = t / 10;
    src = (z == 0) ? bw2 : ((z == 1) ? fw2 : pw2); dst = W2T + (long)z * 1024 * 320;
    K = 300; N = 1024; Kpad = 320; Npad = 1024;
  } else if (bid < 3136) {
    bid -= 2112; bx = bid % 32; by = bid / 32;
    src = enhW; dst = ENHT; K = 1024; N = 1024; Kpad = 1024; Npad = 1024;
  } else {
    bid -= 3136; bx = bid % 64; by = bid / 64;
    src = fusW; dst = FUST; K = 2048; N = 1024; Kpad = 2048; Npad = 1024;
  }
  __shared__ float tile[32][33];
  const int tx = threadIdx.x & 31;
  const int ty = threadIdx.x >> 5;  // 0..7
  const int k0 = bx * 32;
  const int n0 = by * 32;
#pragma unroll
  for (int i = 0; i < 4; i++) {
    int k = k0 + ty + 8 * i;
    int n = n0 + tx;
    tile[ty + 8 * i][tx] = (k < K && n < N) ? src[(long)k * N + n] : 0.f;
  }
  __syncthreads();
#pragma unroll
  for (int i = 0; i < 4; i++) {
    int n = n0 + ty + 8 * i;
    int k = k0 + tx;
    if (n < Npad && k < Kpad) dst[(long)n * Kpad + k] = f2bf(tile[tx][ty + 8 * i]);
  }
}

// ------------------------------- GEMM 128x128 -------------------------------
// A (z-select among A0/A1/A2): bf16 [M][lda], or f32 when AF32=1 (direct
// global_load_lds staging, cvt at fragment read).  Bt [N][ldb] bf16 (z via
// sBz).  C per MODE.
// MODE 0: bias+relu -> bf16 ; MODE 1: bias -> bf16 ;
// MODE 2: sigmoid(acc+bias)*common -> bf16 at col offset ; MODE 3: bias -> f32
template <int MODE, int AF32>
__global__ void cfe_gemm128(const void* __restrict__ A0, const void* __restrict__ A1,
                            const void* __restrict__ A2, int lda,
                            const uint16_t* __restrict__ Bt, long sBz, int ldb,
                            void* __restrict__ C, long sCz, int ldc, int colofs,
                            const float* __restrict__ bias0,
                            const float* __restrict__ bias1,
                            const float* __restrict__ bias2, int biasN,
                            const uint16_t* __restrict__ common, int K) {
  const int z = blockIdx.z;
  const void* Av = (z == 0) ? A0 : ((z == 1) ? A1 : A2);
  Bt += (long)z * sBz;
  const float* bias = (z == 0) ? bias0 : ((z == 1) ? bias1 : bias2);

  // XCD-aware swizzle: blocks sharing an A-strip land contiguously on one XCD.
  const int gx = gridDim.x;
  const int lin = blockIdx.y * gx + blockIdx.x;
  const int P = (gx * gridDim.y) >> 3;
  const int v = (lin & 7) * P + (lin >> 3);
  const long bm = (long)(v / gx) * 128;
  const long bn = (long)(v % gx) * 128;

  const int tid = threadIdx.x;
  const int wave = tid >> 6;
  const int lane = tid & 63;
  const int wm = wave >> 1;  // 0..1
  const int wn = wave & 1;

  // AF32: As holds f32 [128][32] (16KB).  else bf16 [128][32] (8KB).
  __shared__ __attribute__((aligned(16))) uint16_t As[AF32 ? 128 * 64 : 128 * 32];
  __shared__ __attribute__((aligned(16))) uint16_t Bs[128 * 32];

  floatx4 acc[4][4];
#pragma unroll
  for (int i = 0; i < 4; i++)
#pragma unroll
    for (int j = 0; j < 4; j++) acc[i][j] = (floatx4){0.f, 0.f, 0.f, 0.f};

  // ---- bf16 staging (B always; A when !AF32) -------------------------------
  // Per wave: 32 rows; one gload16 issue = 16 rows x 4 lanes x 16B.
  // Swizzle: physical 16B-granule g holds logical granule g ^ ((row>>1)&3).
  // Applied via the per-lane GLOBAL source offset (LDS dest stays linear).
  const int lrow = lane >> 2;                       // 0..15
  const int lcolB = (((lane & 3) ^ ((lrow >> 1) & 3)) * 8);  // swizzled src col
  const uint16_t* Bp = Bt + (bn + wave * 32 + lrow) * (long)ldb + lcolB;
  uint16_t* BsW0 = &Bs[(wave * 32) * 32];
  uint16_t* BsW1 = &Bs[(wave * 32 + 16) * 32];
  const uint16_t* Ap = nullptr;
  uint16_t* AsW0 = &As[(wave * 32) * 32];
  uint16_t* AsW1 = &As[(wave * 32 + 16) * 32];
  if constexpr (!AF32) {
    Ap = (const uint16_t*)Av + (bm + wave * 32 + lrow) * (long)lda + lcolB;
  }

  // ---- f32 A staging (AF32) ------------------------------------------------
  // Per wave: 32 rows x 128B; one gload16 issue = 8 rows x 8 lanes x 16B.
  // Swizzle: phys 32B-granule ^= row&3, phys 16B-half ^= (row>>2)&1 -> 2-way.
  const float* ApS = nullptr;
  char* AsB = nullptr;
  if constexpr (AF32) {
    const int r_in = lane >> 3;        // 0..7 row within issue
    const int gpos = (lane & 7) >> 1;  // 0..3 phys 32B granule
    const int halfp = lane & 1;        // phys 16B half
    const int scol = ((gpos ^ (r_in & 3)) << 3) | ((halfp ^ ((r_in >> 2) & 1)) << 2);
    ApS = (const float*)Av + (bm + wave * 32 + r_in) * (long)lda + scol;
    AsB = (char*)As + (wave * 32) * 128;
  }

  // ---- fragment read bases -------------------------------------------------
  const int fr = lane & 15;
  const int fq = lane >> 4;  // 0..3
  const int swr = (fr >> 1) & 3;  // bf16 read swizzle (matches lcolB)
  const uint16_t* ArBase = &As[(wm * 64 + fr) * 32 + (fq ^ swr) * 8];
  const uint16_t* BrBase = &Bs[(wn * 64 + fr) * 32 + (fq ^ swr) * 8];
  // f32 read: row&3 == fr&3, (row>>2)&1 == (fr>>2)&1 (mi*16 doesn't touch them)
  const int ga = fq ^ (fr & 3);
  const int hb = (fr >> 2) & 1;
  const float* AfBase = (const float*)As + (wm * 64 + fr) * 32 + ga * 8;

  for (int k0 = 0; k0 < K; k0 += 32) {
    if constexpr (AF32) {
      gload16(ApS + k0, AsB);
      gload16(ApS + 8 * (long)lda + k0, AsB + 1024);
      gload16(ApS + 16 * (long)lda + k0, AsB + 2048);
      gload16(ApS + 24 * (long)lda + k0, AsB + 3072);
    } else {
      gload16(Ap + k0, AsW0);
      gload16(Ap + 16 * (long)lda + k0, AsW1);
    }
    gload16(Bp + k0, BsW0);
    gload16(Bp + 16 * (long)ldb + k0, BsW1);
    __syncthreads();

    short8 a[4], b[4];
    if constexpr (AF32) {
#pragma unroll
      for (int mi = 0; mi < 4; mi++) {
        const float* Af = AfBase + mi * 512;
        float4 lo = *(const float4*)(Af + hb * 4);        // logical cols fq*8..+3
        float4 hi = *(const float4*)(Af + (hb ^ 1) * 4);  // logical cols fq*8+4..+7
        a[mi] = pack8(lo, hi);
      }
    } else {
#pragma unroll
      for (int mi = 0; mi < 4; mi++) a[mi] = *(const short8*)(ArBase + mi * 512);
    }
#pragma unroll
    for (int ni = 0; ni < 4; ni++) b[ni] = *(const short8*)(BrBase + ni * 512);
#pragma unroll
    for (int mi = 0; mi < 4; mi++)
#pragma unroll
      for (int ni = 0; ni < 4; ni++)
        acc[mi][ni] = __builtin_amdgcn_mfma_f32_16x16x32_bf16(
            __builtin_bit_cast(bf16x8, a[mi]), __builtin_bit_cast(bf16x8, b[ni]),
            acc[mi][ni], 0, 0, 0);
    __syncthreads();
  }

  // epilogue: D[row=fq*4+r][col=fr] per 16x16 tile
#pragma unroll
  for (int mi = 0; mi < 4; mi++) {
    long row = bm + wm * 64 + mi * 16 + fq * 4;
#pragma unroll
    for (int ni = 0; ni < 4; ni++) {
      long col = bn + wn * 64 + ni * 16 + fr;
      float bv = (col < biasN) ? bias[col] : 0.f;
#pragma unroll
      for (int r = 0; r < 4; r++) {
        float vv = acc[mi][ni][r] + bv;
        long idx = (row + r) * (long)ldc + colofs + col;
        if constexpr (MODE == 0) {
          ((uint16_t*)C)[(long)z * sCz + idx] = f2bf(fmaxf(vv, 0.f));
        } else if constexpr (MODE == 1) {
          ((uint16_t*)C)[(long)z * sCz + idx] = f2bf(vv);
        } else if constexpr (MODE == 2) {
          float c = bf2f(common[(row + r) * 1024 + col]);
          float s = 1.f / (1.f + __expf(-vv));
          ((uint16_t*)C)[idx] = f2bf(c * s);
        } else {
          ((float*)C)[idx] = vv;
        }
      }
    }
  }
}

// ------------------------------- pointwise ---------------------------------
// One block per row. E = [eb|ef|ep] bf16, each 16384x1024, contiguous.
__global__ void cfe_pointwise_kernel(const uint16_t* __restrict__ E,
                                     const float* __restrict__ wgW,
                                     const float* __restrict__ wgb,
                                     uint16_t* __restrict__ commonb,
                                     uint16_t* __restrict__ fusedA) {
  const int row = blockIdx.x;
  const int tid = threadIdx.x;
  const long ES = 16384L * 1024;
  const long base = (long)row * 1024 + tid * 4;

  ushort4 u0 = *(const ushort4*)(E + base);
  ushort4 u1 = *(const ushort4*)(E + ES + base);
  ushort4 u2 = *(const ushort4*)(E + 2 * ES + base);
  float eb[4] = {bf2f(u0.x), bf2f(u0.y), bf2f(u0.z), bf2f(u0.w)};
  float ef[4] = {bf2f(u1.x), bf2f(u1.y), bf2f(u1.z), bf2f(u1.w)};
  float ep[4] = {bf2f(u2.x), bf2f(u2.y), bf2f(u2.z), bf2f(u2.w)};

  float vals[9];
#pragma unroll
  for (int i = 0; i < 9; i++) vals[i] = 0.f;
#pragma unroll
  for (int j = 0; j < 4; j++) {
    int h = tid * 4 + j;
    vals[0] += eb[j] * eb[j];
    vals[1] += ef[j] * ef[j];
    vals[2] += ep[j] * ep[j];
    vals[3] += eb[j] * ef[j];
    vals[4] += eb[j] * ep[j];
    vals[5] += ef[j] * ep[j];
#pragma unroll
    for (int c = 0; c < 3; c++)
      vals[6 + c] += eb[j] * wgW[(long)h * 3 + c] +
                     ef[j] * wgW[(long)(1024 + h) * 3 + c] +
                     ep[j] * wgW[(long)(2048 + h) * 3 + c];
  }

#pragma unroll
  for (int i = 0; i < 9; i++) {
    float v = vals[i];
    for (int off = 32; off; off >>= 1) v += __shfl_down(v, off);
    vals[i] = v;
  }
  __shared__ float red[4][9];
  if ((tid & 63) == 0) {
#pragma unroll
    for (int i = 0; i < 9; i++) red[tid >> 6][i] = vals[i];
  }
  __syncthreads();
  float tot[9];
#pragma unroll
  for (int i = 0; i < 9; i++)
    tot[i] = red[0][i] + red[1][i] + red[2][i] + red[3][i];

  const float EPSF = 1e-12f;
  float nb = fmaxf(sqrtf(tot[0]), EPSF);
  float nf = fmaxf(sqrtf(tot[1]), EPSF);
  float np_ = fmaxf(sqrtf(tot[2]), EPSF);
  float s01 = tot[3] / (nb * nf);
  float s02 = tot[4] / (nb * np_);
  float s12 = tot[5] / (nf * np_);
  bool k01 = s01 > 0.6f, k02 = s02 > 0.6f, k12 = s12 > 0.6f;
  bool any = k01 | k02 | k12;
  float z0 = k01 ? s01 : -1e9f;
  float z1 = k02 ? s02 : -1e9f;
  float z2 = k12 ? s12 : -1e9f;
  float zm = fmaxf(z0, fmaxf(z1, z2));
  float w0 = __expf(z0 - zm), w1 = __expf(z1 - zm), w2 = __expf(z2 - zm);
  float wsum = w0 + w1 + w2;
  w0 /= wsum; w1 /= wsum; w2 /= wsum;

  float g0 = tot[6] + wgb[0], g1 = tot[7] + wgb[1], g2 = tot[8] + wgb[2];
  float gm = fmaxf(g0, fmaxf(g1, g2));
  float f0 = __expf(g0 - gm), f1 = __expf(g1 - gm), f2 = __expf(g2 - gm);
  float fs = f0 + f1 + f2;
  f0 /= fs; f1 /= fs; f2 /= fs;

  float inb = 1.f / nb, inf_ = 1.f / nf, inp = 1.f / np_;
  ushort4 co, wf;
  uint16_t cov[4], wfv[4];
#pragma unroll
  for (int j = 0; j < 4; j++) {
    float b = eb[j], f = ef[j], p = ep[j];
    float nbv = b * inb, nfv = f * inf_, npv = p * inp;
    float c01 = (nbv * nfv > 0.6f) ? 0.5f * (b + f) : 0.f;
    float c02 = (nbv * npv > 0.6f) ? 0.5f * (b + p) : 0.f;
    float c12 = (nfv * npv > 0.6f) ? 0.5f * (f + p) : 0.f;
    float ws = w0 * c01 + w1 * c02 + w2 * c12;
    float cm = any ? ws : (b + f + p) * (1.f / 3.f);
    float wfs = f0 * b + f1 * f + f2 * p;
    cov[j] = f2bf(cm);
    wfv[j] = f2bf(wfs);
  }
  co.x = cov[0]; co.y = cov[1]; co.z = cov[2]; co.w = cov[3];
  wf.x = wfv[0]; wf.y = wfv[1]; wf.z = wfv[2]; wf.w = wfv[3];
  *(ushort4*)(commonb + base) = co;
  *(ushort4*)(fusedA + (long)row * 2048 + tid * 4) = wf;
}

// ------------------------------- launcher ----------------------------------
extern "C" void kernel_launch(void* const* d_in, const int* in_sizes, int n_in,
                              void* d_out, int out_size, void* d_ws, size_t ws_size,
                              hipStream_t stream) {
  (void)in_sizes; (void)n_in; (void)out_size; (void)ws_size;
  const float* brics = (const float*)d_in[0];
  const float* fg    = (const float*)d_in[1];
  const float* ph    = (const float*)d_in[2];
  const float* bw1 = (const float*)d_in[3];  const float* bb1 = (const float*)d_in[4];
  const float* bw2 = (const float*)d_in[5];  const float* bb2 = (const float*)d_in[6];
  const float* fw1 = (const float*)d_in[7];  const float* fb1 = (const float*)d_in[8];
  const float* fw2 = (const float*)d_in[9];  const float* fb2 = (const float*)d_in[10];
  const float* pw1 = (const float*)d_in[11]; const float* pb1 = (const float*)d_in[12];
  const float* pw2 = (const float*)d_in[13]; const float* pb2 = (const float*)d_in[14];
  const float* wgW = (const float*)d_in[15]; const float* wgb = (const float*)d_in[16];
  const float* enhW = (const float*)d_in[17]; const float* enhb = (const float*)d_in[18];
  const float* fusW = (const float*)d_in[19]; const float* fusb = (const float*)d_in[20];
  float* out = (float*)d_out;

  // ws layout (~170 MB): [EB 96MB][FA 64MB][weights ~10MB]
  uint16_t* EB   = (uint16_t*)d_ws;            // 3 * 16384*1024 bf16
  uint16_t* FA   = EB + 3L * 16384 * 1024;     // 16384*2048
  uint16_t* W1T  = FA + 16384L * 2048;         // 3 * 384*1024
  uint16_t* W2T  = W1T + 3L * 384 * 1024;      // 3 * 1024*320
  uint16_t* ENHT = W2T + 3L * 1024 * 320;      // 1024*1024
  uint16_t* FUST = ENHT + 1024L * 1024;        // 1024*2048
  // d_out doubles as scratch before the final GEMM overwrites it:
  uint16_t* YB   = (uint16_t*)d_out;           // 3 * 16384*384 (36MB <= 64MB)
  uint16_t* COM  = (uint16_t*)d_out;           // 16384*1024 (32MB; after YB dead)

  // all weight transposes in one launch
  cfe_transpose_all<<<5184, 256, 0, stream>>>(
      bw1, fw1, pw1, bw2, fw2, pw2, enhW, fusW, W1T, W2T, ENHT, FUST);

  // GEMM1: Y = relu(X @ W1 + b1)   M=16384 N=384 K=1024, A = f32 inputs
  cfe_gemm128<0, 1><<<dim3(3, 128, 3), 256, 0, stream>>>(
      brics, fg, ph, 1024, W1T, 384L * 1024, 1024,
      YB, 16384L * 384, 384, 0, bb1, fb1, pb1, 300, nullptr, 1024);

  // GEMM2: E = Y @ W2 + b2         M=16384 N=1024 K=320
  cfe_gemm128<1, 0><<<dim3(8, 128, 3), 256, 0, stream>>>(
      YB, YB + 16384L * 384, YB + 2 * 16384L * 384, 384, W2T, 1024L * 320, 320,
      EB, 16384L * 1024, 1024, 0, bb2, fb2, pb2, 1024, nullptr, 320);

  // pointwise: common (-> d_out region) + weighted_fp_sum (-> FA left half)
  cfe_pointwise_kernel<<<16384, 256, 0, stream>>>(EB, wgW, wgb, COM, FA);

  // enh: FA[:,1024:] = common * sigmoid(common @ enhW + enhb)
  cfe_gemm128<2, 0><<<dim3(8, 128, 1), 256, 0, stream>>>(
      COM, COM, COM, 1024, ENHT, 0, 1024,
      FA, 0, 2048, 1024, enhb, enhb, enhb, 1024, COM, 1024);

  // fused: out = FA @ fusW + fusb   M=16384 N=1024 K=2048
  cfe_gemm128<3, 0><<<dim3(8, 128, 1), 256, 0, stream>>>(
      FA, FA, FA, 2048, FUST, 0, 2048,
      out, 0, 1024, 0, fusb, fusb, fusb, 1024, nullptr, 2048);
}

// Round 2
// 545.904 us; speedup vs baseline: 1.0295x; 1.0295x over previous
//
#include <hip/hip_runtime.h>
#include <stdint.h>

// ---------------------------------------------------------------------------
// CommonFeatureExtractor on MI355X.  Round 6.
// Changes vs round 5 (562 us; GEMM1 134 us, MfmaUtil 11.3%, conflicts 0):
//  - ALL GEMMs: T3+T4 double-buffered pipeline with COUNTED vmcnt.
//    Old: gload_lds -> __syncthreads (implicit s_waitcnt vmcnt(0) drain!)
//         -> ds_read+MFMA -> __syncthreads.  The drain exposes full load
//         latency every K-step (m233: ~72% of 2-phase time) -> MfmaUtil 12%.
//    New: stage tile t+1 into buf^1, s_waitcnt vmcnt(L) (only tile-t's own
//         loads), raw s_barrier, compute buf, sched_barrier-pinned, raw
//         s_barrier.  Next tile's loads stay in flight across the barriers
//         and the MFMA section (m218: counted-vs-drain0 +38-73%).
//    Correctness: per-wave vmcnt(L) before barrier-1 => tile t complete in
//    LDS for all waves; barrier-2 after lgkm-complete ds_reads => no buffer
//    overwritten early.  LDS: GEMM1 48KB (3 blk/CU), bf16 GEMMs 32KB.
//  - Kept from round 5: conflict-free swizzles (pre-swizzled global source +
//    swizzled read; now on the critical path where they matter), f32 A staged
//    direct via gload_lds, cvt on read (hidden under the pipeline now).
// Kept: XCD swizzle, merged transpose, buffer aliasing, MODE epilogues.
// ---------------------------------------------------------------------------

typedef __attribute__((ext_vector_type(8))) __bf16 bf16x8;
typedef __attribute__((ext_vector_type(8))) short short8;
typedef __attribute__((ext_vector_type(4))) float floatx4;

__device__ __forceinline__ uint16_t f2bf(float f) {
  __bf16 h = (__bf16)f;                      // native RNE cvt on gfx950
  return __builtin_bit_cast(uint16_t, h);
}
__device__ __forceinline__ float bf2f(uint16_t h) {
  union { uint32_t u; float f; } v; v.u = ((uint32_t)h) << 16;
  return v.f;
}
__device__ __forceinline__ short8 pack8(float4 a, float4 b) {
  union { __bf16 h[8]; short8 s; } u;
  u.h[0] = (__bf16)a.x; u.h[1] = (__bf16)a.y; u.h[2] = (__bf16)a.z; u.h[3] = (__bf16)a.w;
  u.h[4] = (__bf16)b.x; u.h[5] = (__bf16)b.y; u.h[6] = (__bf16)b.z; u.h[7] = (__bf16)b.w;
  return u.s;
}
__device__ __forceinline__ void gload16(const void* g, void* l) {
  __builtin_amdgcn_global_load_lds(
      (const __attribute__((address_space(1))) void*)g,
      (__attribute__((address_space(3))) void*)l, 16, 0, 0);
}

// ------------- merged transpose + convert: dst[n][k] = src[k][n] ------------
// Segments: W1T 3x(32x12)=1152 | W2T 3x(10x32)=960 | ENHT 32x32=1024 |
//           FUST 64x32=2048   -> 5184 blocks total.
__global__ void cfe_transpose_all(const float* __restrict__ bw1, const float* __restrict__ fw1,
                                  const float* __restrict__ pw1, const float* __restrict__ bw2,
                                  const float* __restrict__ fw2, const float* __restrict__ pw2,
                                  const float* __restrict__ enhW, const float* __restrict__ fusW,
                                  uint16_t* __restrict__ W1T, uint16_t* __restrict__ W2T,
                                  uint16_t* __restrict__ ENHT, uint16_t* __restrict__ FUST) {
  int bid = blockIdx.x;
  const float* src; uint16_t* dst; int K, N, Kpad, Npad, bx, by;
  if (bid < 1152) {
    int z = bid / 384, t = bid % 384; bx = t % 32; by = t / 32;
    src = (z == 0) ? bw1 : ((z == 1) ? fw1 : pw1); dst = W1T + (long)z * 384 * 1024;
    K = 1024; N = 300; Kpad = 1024; Npad = 384;
  } else if (bid < 2112) {
    bid -= 1152; int z = bid / 320, t = bid % 320; bx = t % 10; by = t / 10;
    src = (z == 0) ? bw2 : ((z == 1) ? fw2 : pw2); dst = W2T + (long)z * 1024 * 320;
    K = 300; N = 1024; Kpad = 320; Npad = 1024;
  } else if (bid < 3136) {
    bid -= 2112; bx = bid % 32; by = bid / 32;
    src = enhW; dst = ENHT; K = 1024; N = 1024; Kpad = 1024; Npad = 1024;
  } else {
    bid -= 3136; bx = bid % 64; by = bid / 64;
    src = fusW; dst = FUST; K = 2048; N = 1024; Kpad = 2048; Npad = 1024;
  }
  __shared__ float tile[32][33];
  const int tx = threadIdx.x & 31;
  const int ty = threadIdx.x >> 5;  // 0..7
  const int k0 = bx * 32;
  const int n0 = by * 32;
#pragma unroll
  for (int i = 0; i < 4; i++) {
    int k = k0 + ty + 8 * i;
    int n = n0 + tx;
    tile[ty + 8 * i][tx] = (k < K && n < N) ? src[(long)k * N + n] : 0.f;
  }
  __syncthreads();
#pragma unroll
  for (int i = 0; i < 4; i++) {
    int n = n0 + ty + 8 * i;
    int k = k0 + tx;
    if (n < Npad && k < Kpad) dst[(long)n * Kpad + k] = f2bf(tile[tx][ty + 8 * i]);
  }
}

// ------------------------------- GEMM 128x128 -------------------------------
// A (z-select among A0/A1/A2): bf16 [M][lda], or f32 when AF32=1 (direct
// global_load_lds staging, cvt at fragment read).  Bt [N][ldb] bf16 (z via
// sBz).  C per MODE.  Double-buffered LDS, counted-vmcnt pipeline.
// MODE 0: bias+relu -> bf16 ; MODE 1: bias -> bf16 ;
// MODE 2: sigmoid(acc+bias)*common -> bf16 at col offset ; MODE 3: bias -> f32
template <int MODE, int AF32>
__global__ void cfe_gemm128(const void* __restrict__ A0, const void* __restrict__ A1,
                            const void* __restrict__ A2, int lda,
                            const uint16_t* __restrict__ Bt, long sBz, int ldb,
                            void* __restrict__ C, long sCz, int ldc, int colofs,
                            const float* __restrict__ bias0,
                            const float* __restrict__ bias1,
                            const float* __restrict__ bias2, int biasN,
                            const uint16_t* __restrict__ common, int K) {
  const int z = blockIdx.z;
  const void* Av = (z == 0) ? A0 : ((z == 1) ? A1 : A2);
  Bt += (long)z * sBz;
  const float* bias = (z == 0) ? bias0 : ((z == 1) ? bias1 : bias2);

  // XCD-aware swizzle: blocks sharing an A-strip land contiguously on one XCD.
  const int gx = gridDim.x;
  const int lin = blockIdx.y * gx + blockIdx.x;
  const int P = (gx * gridDim.y) >> 3;
  const int v = (lin & 7) * P + (lin >> 3);
  const long bm = (long)(v / gx) * 128;
  const long bn = (long)(v % gx) * 128;

  const int tid = threadIdx.x;
  const int wave = tid >> 6;
  const int lane = tid & 63;
  const int wm = wave >> 1;  // 0..1
  const int wn = wave & 1;

  // Double-buffered LDS.  AF32: As = 2 x f32[128][32] (32KB).
  //                       else: As = 2 x bf16[128][32] (16KB).  Bs likewise.
  constexpr int ASZ16 = AF32 ? 128 * 64 : 128 * 32;  // one As buffer, u16 units
  constexpr int BSZ16 = 128 * 32;                    // one Bs buffer, u16 units
  __shared__ __attribute__((aligned(16))) uint16_t As[2 * ASZ16];
  __shared__ __attribute__((aligned(16))) uint16_t Bs[2 * BSZ16];

  floatx4 acc[4][4];
#pragma unroll
  for (int i = 0; i < 4; i++)
#pragma unroll
    for (int j = 0; j < 4; j++) acc[i][j] = (floatx4){0.f, 0.f, 0.f, 0.f};

  // ---- bf16 staging source (B always; A when !AF32) ------------------------
  // Per wave: 32 rows; one gload16 issue = 16 rows x 4 lanes x 16B.
  // Swizzle: physical 16B-granule g holds logical granule g ^ ((row>>1)&3),
  // applied via the per-lane GLOBAL source offset (LDS dest stays linear).
  const int lrow = lane >> 2;                                // 0..15
  const int lcolB = (((lane & 3) ^ ((lrow >> 1) & 3)) * 8);  // swizzled src col
  const uint16_t* Bp = Bt + (bn + wave * 32 + lrow) * (long)ldb + lcolB;
  const uint16_t* Ap = nullptr;
  if constexpr (!AF32) {
    Ap = (const uint16_t*)Av + (bm + wave * 32 + lrow) * (long)lda + lcolB;
  }

  // ---- f32 A staging source (AF32) -----------------------------------------
  // Per wave: 32 rows x 128B; one gload16 issue = 8 rows x 8 lanes x 16B.
  // Swizzle: phys 32B-granule ^= row&3, phys 16B-half ^= (row>>2)&1 -> 2-way.
  const float* ApS = nullptr;
  if constexpr (AF32) {
    const int r_in = lane >> 3;        // 0..7 row within issue
    const int gpos = (lane & 7) >> 1;  // 0..3 phys 32B granule
    const int halfp = lane & 1;        // phys 16B half
    const int scol = ((gpos ^ (r_in & 3)) << 3) | ((halfp ^ ((r_in >> 2) & 1)) << 2);
    ApS = (const float*)Av + (bm + wave * 32 + r_in) * (long)lda + scol;
  }

  // L = gload16 issues per wave per tile (for counted vmcnt)
  // AF32: 4 (A) + 2 (B) = 6 ; bf16: 2 (A) + 2 (B) = 4.
  auto stage = [&](int k0, int p) {
    if constexpr (AF32) {
      char* AsBp = (char*)As + p * (ASZ16 * 2) + (wave * 32) * 128;
      gload16(ApS + k0, AsBp);
      gload16(ApS + 8 * (long)lda + k0, AsBp + 1024);
      gload16(ApS + 16 * (long)lda + k0, AsBp + 2048);
      gload16(ApS + 24 * (long)lda + k0, AsBp + 3072);
    } else {
      uint16_t* AsP = As + p * ASZ16 + (wave * 32) * 32;
      gload16(Ap + k0, AsP);
      gload16(Ap + 16 * (long)lda + k0, AsP + 16 * 32);
    }
    uint16_t* BsP = Bs + p * BSZ16 + (wave * 32) * 32;
    gload16(Bp + k0, BsP);
    gload16(Bp + 16 * (long)ldb + k0, BsP + 16 * 32);
  };

  // ---- fragment read bases (parity added per tile) -------------------------
  const int fr = lane & 15;
  const int fq = lane >> 4;       // 0..3
  const int swr = (fr >> 1) & 3;  // bf16 read swizzle (matches lcolB)
  const uint16_t* ArBase = &As[(wm * 64 + fr) * 32 + (fq ^ swr) * 8];
  const uint16_t* BrBase = &Bs[(wn * 64 + fr) * 32 + (fq ^ swr) * 8];
  // f32 read: row&3 == fr&3, (row>>2)&1 == (fr>>2)&1 (mi*16 doesn't touch them)
  const int ga = fq ^ (fr & 3);
  const int hb = (fr >> 2) & 1;
  const float* AfBase = (const float*)As + (wm * 64 + fr) * 32 + ga * 8;

  auto compute_tile = [&](int p) {
    short8 a[4], b[4];
    if constexpr (AF32) {
      const float* Af = AfBase + p * (ASZ16 / 2);
#pragma unroll
      for (int mi = 0; mi < 4; mi++) {
        const float* Afm = Af + mi * 512;
        float4 lo = *(const float4*)(Afm + hb * 4);        // logical cols fq*8..+3
        float4 hi = *(const float4*)(Afm + (hb ^ 1) * 4);  // logical cols fq*8+4..+7
        a[mi] = pack8(lo, hi);
      }
    } else {
      const uint16_t* Ar = ArBase + p * ASZ16;
#pragma unroll
      for (int mi = 0; mi < 4; mi++) a[mi] = *(const short8*)(Ar + mi * 512);
    }
    const uint16_t* Br = BrBase + p * BSZ16;
#pragma unroll
    for (int ni = 0; ni < 4; ni++) b[ni] = *(const short8*)(Br + ni * 512);
#pragma unroll
    for (int mi = 0; mi < 4; mi++)
#pragma unroll
      for (int ni = 0; ni < 4; ni++)
        acc[mi][ni] = __builtin_amdgcn_mfma_f32_16x16x32_bf16(
            __builtin_bit_cast(bf16x8, a[mi]), __builtin_bit_cast(bf16x8, b[ni]),
            acc[mi][ni], 0, 0, 0);
  };

  // ---- pipelined K-loop ----------------------------------------------------
  // iter t: tile t+1's loads issued, then wait ONLY tile t's (vmcnt(L)),
  // raw barrier (no drain), compute, raw barrier.  Tile t+1's loads remain
  // in flight across the barriers and the MFMA section.
  const int nt = K >> 5;
  int pb = 0;
  stage(0, 0);
  for (int t = 0; t + 1 < nt; ++t, pb ^= 1) {
    stage((t + 1) << 5, pb ^ 1);
    if constexpr (AF32) {
      asm volatile("s_waitcnt vmcnt(6)" ::: "memory");
    } else {
      asm volatile("s_waitcnt vmcnt(4)" ::: "memory");
    }
    __builtin_amdgcn_s_barrier();
    __builtin_amdgcn_sched_barrier(0);
    compute_tile(pb);
    __builtin_amdgcn_sched_barrier(0);
    __builtin_amdgcn_s_barrier();
  }
  // last tile: drain everything
  asm volatile("s_waitcnt vmcnt(0)" ::: "memory");
  __builtin_amdgcn_s_barrier();
  __builtin_amdgcn_sched_barrier(0);
  compute_tile(pb);

  // epilogue: D[row=fq*4+r][col=fr] per 16x16 tile
#pragma unroll
  for (int mi = 0; mi < 4; mi++) {
    long row = bm + wm * 64 + mi * 16 + fq * 4;
#pragma unroll
    for (int ni = 0; ni < 4; ni++) {
      long col = bn + wn * 64 + ni * 16 + fr;
      float bv = (col < biasN) ? bias[col] : 0.f;
#pragma unroll
      for (int r = 0; r < 4; r++) {
        float vv = acc[mi][ni][r] + bv;
        long idx = (row + r) * (long)ldc + colofs + col;
        if constexpr (MODE == 0) {
          ((uint16_t*)C)[(long)z * sCz + idx] = f2bf(fmaxf(vv, 0.f));
        } else if constexpr (MODE == 1) {
          ((uint16_t*)C)[(long)z * sCz + idx] = f2bf(vv);
        } else if constexpr (MODE == 2) {
          float c = bf2f(common[(row + r) * 1024 + col]);
          float s = 1.f / (1.f + __expf(-vv));
          ((uint16_t*)C)[idx] = f2bf(c * s);
        } else {
          ((float*)C)[idx] = vv;
        }
      }
    }
  }
}

// ------------------------------- pointwise ---------------------------------
// One block per row. E = [eb|ef|ep] bf16, each 16384x1024, contiguous.
__global__ void cfe_pointwise_kernel(const uint16_t* __restrict__ E,
                                     const float* __restrict__ wgW,
                                     const float* __restrict__ wgb,
                                     uint16_t* __restrict__ commonb,
                                     uint16_t* __restrict__ fusedA) {
  const int row = blockIdx.x;
  const int tid = threadIdx.x;
  const long ES = 16384L * 1024;
  const long base = (long)row * 1024 + tid * 4;

  ushort4 u0 = *(const ushort4*)(E + base);
  ushort4 u1 = *(const ushort4*)(E + ES + base);
  ushort4 u2 = *(const ushort4*)(E + 2 * ES + base);
  float eb[4] = {bf2f(u0.x), bf2f(u0.y), bf2f(u0.z), bf2f(u0.w)};
  float ef[4] = {bf2f(u1.x), bf2f(u1.y), bf2f(u1.z), bf2f(u1.w)};
  float ep[4] = {bf2f(u2.x), bf2f(u2.y), bf2f(u2.z), bf2f(u2.w)};

  float vals[9];
#pragma unroll
  for (int i = 0; i < 9; i++) vals[i] = 0.f;
#pragma unroll
  for (int j = 0; j < 4; j++) {
    int h = tid * 4 + j;
    vals[0] += eb[j] * eb[j];
    vals[1] += ef[j] * ef[j];
    vals[2] += ep[j] * ep[j];
    vals[3] += eb[j] * ef[j];
    vals[4] += eb[j] * ep[j];
    vals[5] += ef[j] * ep[j];
#pragma unroll
    for (int c = 0; c < 3; c++)
      vals[6 + c] += eb[j] * wgW[(long)h * 3 + c] +
                     ef[j] * wgW[(long)(1024 + h) * 3 + c] +
                     ep[j] * wgW[(long)(2048 + h) * 3 + c];
  }

#pragma unroll
  for (int i = 0; i < 9; i++) {
    float v = vals[i];
    for (int off = 32; off; off >>= 1) v += __shfl_down(v, off);
    vals[i] = v;
  }
  __shared__ float red[4][9];
  if ((tid & 63) == 0) {
#pragma unroll
    for (int i = 0; i < 9; i++) red[tid >> 6][i] = vals[i];
  }
  __syncthreads();
  float tot[9];
#pragma unroll
  for (int i = 0; i < 9; i++)
    tot[i] = red[0][i] + red[1][i] + red[2][i] + red[3][i];

  const float EPSF = 1e-12f;
  float nb = fmaxf(sqrtf(tot[0]), EPSF);
  float nf = fmaxf(sqrtf(tot[1]), EPSF);
  float np_ = fmaxf(sqrtf(tot[2]), EPSF);
  float s01 = tot[3] / (nb * nf);
  float s02 = tot[4] / (nb * np_);
  float s12 = tot[5] / (nf * np_);
  bool k01 = s01 > 0.6f, k02 = s02 > 0.6f, k12 = s12 > 0.6f;
  bool any = k01 | k02 | k12;
  float z0 = k01 ? s01 : -1e9f;
  float z1 = k02 ? s02 : -1e9f;
  float z2 = k12 ? s12 : -1e9f;
  float zm = fmaxf(z0, fmaxf(z1, z2));
  float w0 = __expf(z0 - zm), w1 = __expf(z1 - zm), w2 = __expf(z2 - zm);
  float wsum = w0 + w1 + w2;
  w0 /= wsum; w1 /= wsum; w2 /= wsum;

  float g0 = tot[6] + wgb[0], g1 = tot[7] + wgb[1], g2 = tot[8] + wgb[2];
  float gm = fmaxf(g0, fmaxf(g1, g2));
  float f0 = __expf(g0 - gm), f1 = __expf(g1 - gm), f2 = __expf(g2 - gm);
  float fs = f0 + f1 + f2;
  f0 /= fs; f1 /= fs; f2 /= fs;

  float inb = 1.f / nb, inf_ = 1.f / nf, inp = 1.f / np_;
  ushort4 co, wf;
  uint16_t cov[4], wfv[4];
#pragma unroll
  for (int j = 0; j < 4; j++) {
    float b = eb[j], f = ef[j], p = ep[j];
    float nbv = b * inb, nfv = f * inf_, npv = p * inp;
    float c01 = (nbv * nfv > 0.6f) ? 0.5f * (b + f) : 0.f;
    float c02 = (nbv * npv > 0.6f) ? 0.5f * (b + p) : 0.f;
    float c12 = (nfv * npv > 0.6f) ? 0.5f * (f + p) : 0.f;
    float ws = w0 * c01 + w1 * c02 + w2 * c12;
    float cm = any ? ws : (b + f + p) * (1.f / 3.f);
    float wfs = f0 * b + f1 * f + f2 * p;
    cov[j] = f2bf(cm);
    wfv[j] = f2bf(wfs);
  }
  co.x = cov[0]; co.y = cov[1]; co.z = cov[2]; co.w = cov[3];
  wf.x = wfv[0]; wf.y = wfv[1]; wf.z = wfv[2]; wf.w = wfv[3];
  *(ushort4*)(commonb + base) = co;
  *(ushort4*)(fusedA + (long)row * 2048 + tid * 4) = wf;
}

// ------------------------------- launcher ----------------------------------
extern "C" void kernel_launch(void* const* d_in, const int* in_sizes, int n_in,
                              void* d_out, int out_size, void* d_ws, size_t ws_size,
                              hipStream_t stream) {
  (void)in_sizes; (void)n_in; (void)out_size; (void)ws_size;
  const float* brics = (const float*)d_in[0];
  const float* fg    = (const float*)d_in[1];
  const float* ph    = (const float*)d_in[2];
  const float* bw1 = (const float*)d_in[3];  const float* bb1 = (const float*)d_in[4];
  const float* bw2 = (const float*)d_in[5];  const float* bb2 = (const float*)d_in[6];
  const float* fw1 = (const float*)d_in[7];  const float* fb1 = (const float*)d_in[8];
  const float* fw2 = (const float*)d_in[9];  const float* fb2 = (const float*)d_in[10];
  const float* pw1 = (const float*)d_in[11]; const float* pb1 = (const float*)d_in[12];
  const float* pw2 = (const float*)d_in[13]; const float* pb2 = (const float*)d_in[14];
  const float* wgW = (const float*)d_in[15]; const float* wgb = (const float*)d_in[16];
  const float* enhW = (const float*)d_in[17]; const float* enhb = (const float*)d_in[18];
  const float* fusW = (const float*)d_in[19]; const float* fusb = (const float*)d_in[20];
  float* out = (float*)d_out;

  // ws layout (~170 MB): [EB 96MB][FA 64MB][weights ~10MB]
  uint16_t* EB   = (uint16_t*)d_ws;            // 3 * 16384*1024 bf16
  uint16_t* FA   = EB + 3L * 16384 * 1024;     // 16384*2048
  uint16_t* W1T  = FA + 16384L * 2048;         // 3 * 384*1024
  uint16_t* W2T  = W1T + 3L * 384 * 1024;      // 3 * 1024*320
  uint16_t* ENHT = W2T + 3L * 1024 * 320;      // 1024*1024
  uint16_t* FUST = ENHT + 1024L * 1024;        // 1024*2048
  // d_out doubles as scratch before the final GEMM overwrites it:
  uint16_t* YB   = (uint16_t*)d_out;           // 3 * 16384*384 (36MB <= 64MB)
  uint16_t* COM  = (uint16_t*)d_out;           // 16384*1024 (32MB; after YB dead)

  // all weight transposes in one launch
  cfe_transpose_all<<<5184, 256, 0, stream>>>(
      bw1, fw1, pw1, bw2, fw2, pw2, enhW, fusW, W1T, W2T, ENHT, FUST);

  // GEMM1: Y = relu(X @ W1 + b1)   M=16384 N=384 K=1024, A = f32 inputs
  cfe_gemm128<0, 1><<<dim3(3, 128, 3), 256, 0, stream>>>(
      brics, fg, ph, 1024, W1T, 384L * 1024, 1024,
      YB, 16384L * 384, 384, 0, bb1, fb1, pb1, 300, nullptr, 1024);

  // GEMM2: E = Y @ W2 + b2         M=16384 N=1024 K=320
  cfe_gemm128<1, 0><<<dim3(8, 128, 3), 256, 0, stream>>>(
      YB, YB + 16384L * 384, YB + 2 * 16384L * 384, 384, W2T, 1024L * 320, 320,
      EB, 16384L * 1024, 1024, 0, bb2, fb2, pb2, 1024, nullptr, 320);

  // pointwise: common (-> d_out region) + weighted_fp_sum (-> FA left half)
  cfe_pointwise_kernel<<<16384, 256, 0, stream>>>(EB, wgW, wgb, COM, FA);

  // enh: FA[:,1024:] = common * sigmoid(common @ enhW + enhb)
  cfe_gemm128<2, 0><<<dim3(8, 128, 1), 256, 0, stream>>>(
      COM, COM, COM, 1024, ENHT, 0, 1024,
      FA, 0, 2048, 1024, enhb, enhb, enhb, 1024, COM, 1024);

  // fused: out = FA @ fusW + fusb   M=16384 N=1024 K=2048
  cfe_gemm128<3, 0><<<dim3(8, 128, 1), 256, 0, stream>>>(
      FA, FA, FA, 2048, FUST, 0, 2048,
      out, 0, 1024, 0, fusb, fusb, fusb, 1024, nullptr, 2048);
}